// Round 1
// baseline (5447.972 us; speedup 1.0000x reference)
//
#include <hip/hip_runtime.h>

typedef unsigned short u16;
typedef unsigned int u32;
typedef short bf16x8 __attribute__((ext_vector_type(8)));
typedef float f32x4 __attribute__((ext_vector_type(4)));

#define NB 128
#define NL 400
#define NT 30
#define NE 300
#define NHE 512
#define NHD 512
#define NA 512
#define NV 20000
#define KX 832     // padded E+He (812 -> 832)
#define KR 1344    // padded E+He+Hd with gap: emb[0,300) ctx[300,812) gap[812,816) s[816,1328) pad[1328,1344)
#define NVP 20096  // padded vocab rows for energy GEMM

static __device__ __forceinline__ u16 f2b(float x){ u32 u=__float_as_uint(x); u += 0x7FFFu + ((u>>16)&1u); return (u16)(u>>16); }
static __device__ __forceinline__ float b2f(u16 h){ return __uint_as_float(((u32)h)<<16); }
static __device__ __forceinline__ float fsig(float x){ return 1.f/(1.f+__expf(-x)); }
static __device__ __forceinline__ float ftanh(float x){ return 1.f - 2.f/(__expf(2.f*x)+1.f); }

static __device__ __forceinline__ void gll16(const u16* g, u16* l){
  __builtin_amdgcn_global_load_lds((const __attribute__((address_space(1))) void*)g,
                                   (__attribute__((address_space(3))) void*)l, 16, 0, 0);
}

// 128x128 output tile, A[M,K] x B[N,K] (both row-major, bf16), f32 accum.
// 256 threads = 4 waves in 2x2; each wave does 64x64 via 4x4 16x16x32 MFMA frags.
static __device__ __forceinline__ void gemm_core(const u16* A, int lda, const u16* Bm, int ldb,
                                                 int K, u16* lsA, u16* lsB, f32x4 (&acc)[4][4]){
  const int tid = threadIdx.x;
  const int wave = tid>>6, lane = tid&63;
  const int srow = lane>>2, sko = (lane&3)*8;
  const int wm = wave>>1, wn = wave&1;
#pragma unroll
  for (int i=0;i<4;i++)
#pragma unroll
    for (int j=0;j<4;j++)
#pragma unroll
      for (int q=0;q<4;q++) acc[i][j][q] = 0.f;
  for (int kt=0; kt<K; kt+=32){
#pragma unroll
    for (int i=0;i<2;i++){
      const int c = wave*2+i;                 // chunk 0..7: 16 rows each
      const int row = c*16 + srow;
      gll16(A + (size_t)row*lda + kt + sko, lsA + c*512);
      gll16(Bm + (size_t)row*ldb + kt + sko, lsB + c*512);
    }
    __syncthreads();
    bf16x8 aF[4], bF[4];
#pragma unroll
    for (int mi=0;mi<4;mi++) aF[mi] = *(const bf16x8*)(lsA + (wm*64+mi*16+(lane&15))*32 + (lane>>4)*8);
#pragma unroll
    for (int nj=0;nj<4;nj++) bF[nj] = *(const bf16x8*)(lsB + (wn*64+nj*16+(lane&15))*32 + (lane>>4)*8);
#pragma unroll
    for (int mi=0;mi<4;mi++)
#pragma unroll
      for (int nj=0;nj<4;nj++)
        acc[mi][nj] = __builtin_amdgcn_mfma_f32_16x16x32_bf16(aF[mi], bF[nj], acc[mi][nj], 0,0,0);
    __syncthreads();
  }
}

// ---------------- setup kernels ----------------

__global__ __launch_bounds__(256) void k_conv_flat(const float* __restrict__ s, u16* __restrict__ d, long n){
  long i = (long)blockIdx.x*256 + threadIdx.x;
  const long st = (long)gridDim.x*256;
  for (; i<n; i+=st) d[i] = f2b(s[i]);
}

__global__ __launch_bounds__(256) void k_convpad(const float* __restrict__ s, u16* __restrict__ d,
                                                 int srows, int sk, int dk, long total){
  long i = (long)blockIdx.x*256 + threadIdx.x;
  const long st = (long)gridDim.x*256;
  for (; i<total; i+=st){
    int r = (int)(i / dk), k = (int)(i - (long)r*dk);
    d[i] = (r < srows && k < sk) ? f2b(s[(size_t)r*sk + k]) : (u16)0;
  }
}

// read_W (512 x 1324) -> (512 x 1344) with the 4-col gap inserted at 812
__global__ __launch_bounds__(256) void k_conv_readW(const float* __restrict__ s, u16* __restrict__ d){
  long i = (long)blockIdx.x*256 + threadIdx.x;
  const long st = (long)gridDim.x*256;
  const long total = (long)512*KR;
  for (; i<total; i+=st){
    int r = (int)(i / KR), k = (int)(i - (long)r*KR);
    float v = 0.f;
    if (k < 812) v = s[(size_t)r*1324 + k];
    else if (k >= 816 && k < 1328) v = s[(size_t)r*1324 + k - 4];
    d[i] = f2b(v);
  }
}

// att_Ws (A x Hd) -> WsT (Hd x A) bf16
__global__ __launch_bounds__(256) void k_wst(const float* __restrict__ s, u16* __restrict__ d){
  int idx = blockIdx.x*256 + threadIdx.x;
  if (idx < 512*512){
    int a = idx & 511, kk = idx >> 9;
    d[idx] = f2b(s[(size_t)a*512 + kk]);   // d[kk*512+a] = s[a][kk]
  }
}

__global__ __launch_bounds__(256) void k_init(const float* __restrict__ s_in, const float* __restrict__ embed,
                                              float* __restrict__ sbuf0, u16* __restrict__ xgru, u16* __restrict__ xread){
  int idx = blockIdx.x*256 + threadIdx.x;
  if (idx < 65536){                    // s carry + bf16 copy
    int b = idx>>9, j = idx&511;
    float v = s_in[idx];
    sbuf0[idx] = v;
    xread[b*KR + 816 + j] = f2b(v);
    return;
  }
  idx -= 65536;
  if (idx < 65536){                    // ctx0 = 0
    int b = idx>>9, j = idx&511;
    xgru[b*KX + 300 + j] = 0;
    xread[b*KR + 300 + j] = 0;
    return;
  }
  idx -= 65536;
  if (idx < NB*4){                     // xread gap
    int b = idx>>2, j = idx&3;
    xread[b*KR + 812 + j] = 0;
    return;
  }
  idx -= NB*4;
  if (idx < NB*16){                    // xread tail pad
    int b = idx>>4, j = idx&15;
    xread[b*KR + 1328 + j] = 0;
    return;
  }
  idx -= NB*16;
  if (idx < NB*20){                    // xgru pad
    int b = idx/20, j = idx - b*20;
    xgru[b*KX + 812 + j] = 0;
    return;
  }
  idx -= NB*20;
  if (idx < NB*NE){                    // SOS embedding
    int b = idx/NE, k = idx - b*NE;
    u16 hv = f2b(embed[2*NE + k]);
    xgru[b*KX + k] = hv;
    xread[b*KR + k] = hv;
  }
}

// enc_proj = enc @ att_Wh^T, bf16 out. grid (4, 400)
__global__ __launch_bounds__(256) void k_encproj(const u16* __restrict__ A, const u16* __restrict__ Bw, u16* __restrict__ C){
  __shared__ __align__(16) u16 lsA[4096], lsB[4096];
  const int n0 = blockIdx.x*128, m0 = blockIdx.y*128;
  f32x4 acc[4][4];
  gemm_core(A + (size_t)m0*512, 512, Bw + (size_t)n0*512, 512, 512, lsA, lsB, acc);
  const int tid=threadIdx.x, wave=tid>>6, lane=tid&63, wm=wave>>1, wn=wave&1;
#pragma unroll
  for (int mi=0;mi<4;mi++)
#pragma unroll
    for (int nj=0;nj<4;nj++)
#pragma unroll
      for (int q=0;q<4;q++){
        int r = m0 + wm*64 + mi*16 + (lane>>4)*4 + q;
        int c = n0 + wn*64 + nj*16 + (lane&15);
        C[(size_t)r*512 + c] = f2b(acc[mi][nj][q]);
      }
}

// ---------------- per-step kernels ----------------

// grid 24: blocks 0..11 -> gi = xgru @ Wih^T ; 12..23 -> gh = s_bf16 @ Whh^T
__global__ __launch_bounds__(256) void k_gru_gemm(const u16* __restrict__ xgru, const u16* __restrict__ xread,
    const u16* __restrict__ Wih, const u16* __restrict__ Whh, float* __restrict__ gi, float* __restrict__ gh){
  __shared__ __align__(16) u16 lsA[4096], lsB[4096];
  const int bx = blockIdx.x;
  const u16* A; const u16* Bm; float* C; int lda, ldb, K, n0;
  if (bx < 12){ A = xgru;        lda = KX; Bm = Wih + (size_t)bx*128*KX;      ldb = KX;  K = KX;  C = gi; n0 = bx*128; }
  else { int b2 = bx-12; A = xread + 816; lda = KR; Bm = Whh + (size_t)b2*128*512; ldb = 512; K = 512; C = gh; n0 = b2*128; }
  f32x4 acc[4][4];
  gemm_core(A, lda, Bm, ldb, K, lsA, lsB, acc);
  const int tid=threadIdx.x, wave=tid>>6, lane=tid&63, wm=wave>>1, wn=wave&1;
#pragma unroll
  for (int mi=0;mi<4;mi++)
#pragma unroll
    for (int nj=0;nj<4;nj++)
#pragma unroll
      for (int q=0;q<4;q++){
        int r = wm*64 + mi*16 + (lane>>4)*4 + q;
        int c = n0 + wn*64 + nj*16 + (lane&15);
        C[(size_t)r*1536 + c] = acc[mi][nj][q];
      }
}

__global__ __launch_bounds__(256) void k_gru_elem(const float* __restrict__ gi, const float* __restrict__ gh,
  const float* __restrict__ bih, const float* __restrict__ bhh, const float* __restrict__ sold,
  float* __restrict__ snew, u16* __restrict__ xread){
  int idx = blockIdx.x*256 + threadIdx.x;
  int b = idx>>9, j = idx&511;
  const float* gib = gi + (size_t)b*1536;
  const float* ghb = gh + (size_t)b*1536;
  float r = fsig(gib[j] + bih[j] + ghb[j] + bhh[j]);
  float z = fsig(gib[512+j] + bih[512+j] + ghb[512+j] + bhh[512+j]);
  float n = ftanh(gib[1024+j] + bih[1024+j] + r*(ghb[1024+j] + bhh[1024+j]));
  float sn = (1.f-z)*n + z*sold[idx];
  snew[idx] = sn;
  xread[b*KR + 816 + j] = f2b(sn);
}

// one block per batch row: q proj, e = v.tanh(ep+q), masked softmax, ctx, p_copy, copy-slice output
__global__ __launch_bounds__(512) void k_attn(const float* __restrict__ snew, const u16* __restrict__ eproj,
    const u16* __restrict__ encb, const u16* __restrict__ WsT, const float* __restrict__ attb,
    const float* __restrict__ attv, const int* __restrict__ src, const float* __restrict__ copyW,
    const float* __restrict__ copyb, u16* __restrict__ xgru, u16* __restrict__ xread,
    float* __restrict__ pcb, float* __restrict__ out, int t){
  const int tid = threadIdx.x, b = blockIdx.x;
  const int lane = tid&63, wv = tid>>6;
  __shared__ float s_row[512];
  __shared__ float q_lds[512];
  __shared__ float e_lds[NL];
  __shared__ float red[8];
  __shared__ float bc1, bc2, bc3;
  s_row[tid] = snew[b*512 + tid];
  __syncthreads();
  {  // q[tid] = att_b + sum_k s[k]*WsT[k][tid]
    float a0=0,a1=0,a2=0,a3=0;
    const u16* wp = WsT + tid;
#pragma unroll 4
    for (int k=0;k<512;k+=4){
      a0 += s_row[k]   * b2f(wp[(size_t)k*512]);
      a1 += s_row[k+1] * b2f(wp[(size_t)(k+1)*512]);
      a2 += s_row[k+2] * b2f(wp[(size_t)(k+2)*512]);
      a3 += s_row[k+3] * b2f(wp[(size_t)(k+3)*512]);
    }
    q_lds[tid] = attb[tid] + a0+a1+a2+a3;
  }
  __syncthreads();
  float v8[8], q8[8];
#pragma unroll
  for (int j=0;j<8;j++){ v8[j]=attv[lane*8+j]; q8[j]=q_lds[lane*8+j]; }
  for (int l=wv; l<NL; l+=8){          // one wave per source position
    const u16* ep = eproj + ((size_t)b*NL + l)*512 + lane*8;
    const uint4 pk = *(const uint4*)ep;
    float acc=0;
    const u32 wsv[4] = {pk.x, pk.y, pk.z, pk.w};
#pragma unroll
    for (int j2=0;j2<4;j2++){
      float x0 = b2f((u16)(wsv[j2]&0xFFFFu)) + q8[2*j2];
      float x1 = b2f((u16)(wsv[j2]>>16))     + q8[2*j2+1];
      acc += v8[2*j2]*ftanh(x0) + v8[2*j2+1]*ftanh(x1);
    }
    for (int off2=32; off2; off2>>=1) acc += __shfl_xor(acc, off2);
    if (lane==0) e_lds[l] = (src[b*NL + l]==0) ? -INFINITY : acc;
  }
  __syncthreads();
  float ev = (tid<NL)? e_lds[tid] : -INFINITY;
  float mx = ev;
  for (int off=32; off; off>>=1) mx = fmaxf(mx, __shfl_xor(mx, off));
  if (lane==0) red[wv]=mx;
  __syncthreads();
  if (tid==0){ float m=red[0]; for(int i2=1;i2<8;i2++) m=fmaxf(m,red[i2]); bc1=m; }
  __syncthreads();
  float p = (tid<NL)? __expf(ev - bc1) : 0.f;
  float sm = p;
  for (int off=32; off; off>>=1) sm += __shfl_xor(sm, off);
  if (lane==0) red[wv]=sm;
  __syncthreads();
  if (tid==0){ float s2=0; for(int i2=0;i2<8;i2++) s2+=red[i2]; bc2=s2; }
  __syncthreads();
  if (tid<NL) e_lds[tid] = p / bc2;    // e_lds now holds attn
  __syncthreads();
  // ctx[tid] = sum_l attn[l] * enc[b,l,tid]
  float c0=0,c1=0,c2=0,c3=0;
  const u16* eb = encb + (size_t)b*NL*512 + tid;
#pragma unroll 4
  for (int l=0;l<NL;l+=4){
    c0 += e_lds[l]   * b2f(eb[(size_t)l*512]);
    c1 += e_lds[l+1] * b2f(eb[(size_t)(l+1)*512]);
    c2 += e_lds[l+2] * b2f(eb[(size_t)(l+2)*512]);
    c3 += e_lds[l+3] * b2f(eb[(size_t)(l+3)*512]);
  }
  const float ctx = c0+c1+c2+c3;
  const u16 cb = f2b(ctx);
  xgru[b*KX + 300 + tid] = cb;
  xread[b*KR + 300 + tid] = cb;
  // p_copy
  float part = s_row[tid]*copyW[tid] + ctx*copyW[512+tid];
  for (int off=32; off; off>>=1) part += __shfl_xor(part, off);
  if (lane==0) red[wv]=part;
  __syncthreads();
  if (tid==0){ float s2=0; for(int i2=0;i2<8;i2++) s2+=red[i2]; bc3 = fsig(s2 + copyb[0]); pcb[b]=bc3; }
  __syncthreads();
  const float pcv = bc3;
  float* ob = out + ((size_t)b*NT + t)*(NV+NL) + NV;
  if (tid<NL) ob[tid] = __logf(pcv*e_lds[tid] + 1e-12f);
}

// rvec = xread @ read_W^T + b, maxout(2) -> m bf16. grid 4
__global__ __launch_bounds__(256) void k_read_maxout(const u16* __restrict__ xread, const u16* __restrict__ Wr,
    const float* __restrict__ readb, u16* __restrict__ mbf){
  __shared__ __align__(16) u16 lsA[4096], lsB[4096];
  const int n0 = blockIdx.x*128;
  f32x4 acc[4][4];
  gemm_core(xread, KR, Wr + (size_t)n0*KR, KR, KR, lsA, lsB, acc);
  const int tid=threadIdx.x, wave=tid>>6, lane=tid&63, wm=wave>>1, wn=wave&1;
#pragma unroll
  for (int mi=0;mi<4;mi++)
#pragma unroll
    for (int nj=0;nj<4;nj++)
#pragma unroll
      for (int q=0;q<4;q++){
        int r = wm*64 + mi*16 + (lane>>4)*4 + q;
        int c = n0 + wn*64 + nj*16 + (lane&15);
        float v = acc[mi][nj][q] + readb[c];
        float o = __shfl_xor(v, 1);
        float mx2 = fmaxf(v, o);
        if (!(lane&1)) mbf[(size_t)r*256 + (c>>1)] = f2b(mx2);
      }
}

// energy = m @ read_Wo^T. grid 157
__global__ __launch_bounds__(256) void k_energy(const u16* __restrict__ mbf, const u16* __restrict__ Wo, float* __restrict__ energy){
  __shared__ __align__(16) u16 lsA[4096], lsB[4096];
  const int n0 = blockIdx.x*128;
  f32x4 acc[4][4];
  gemm_core(mbf, 256, Wo + (size_t)n0*256, 256, 256, lsA, lsB, acc);
  const int tid=threadIdx.x, wave=tid>>6, lane=tid&63, wm=wave>>1, wn=wave&1;
#pragma unroll
  for (int mi=0;mi<4;mi++)
#pragma unroll
    for (int nj=0;nj<4;nj++)
#pragma unroll
      for (int q=0;q<4;q++){
        int r = wm*64 + mi*16 + (lane>>4)*4 + q;
        int c = n0 + wn*64 + nj*16 + (lane&15);
        if (c < NV) energy[(size_t)r*NV + c] = acc[mi][nj][q];
      }
}

// blocks 0..127: per-b LSE + vocab log-probs. blocks 128..277: gather emb for step t+1.
__global__ __launch_bounds__(256) void k_out_emb(const float* __restrict__ energy, const float* __restrict__ pcb,
    float* __restrict__ out, int t, const int* __restrict__ target, const float* __restrict__ embed,
    u16* __restrict__ xgru, u16* __restrict__ xread){
  const int tid = threadIdx.x;
  if (blockIdx.x >= NB){
    int ei = (blockIdx.x - NB)*256 + tid;
    if (ei < NB*NE){
      int b = ei/NE, k = ei - b*NE;
      int w2 = target[b*NT + t]; if ((u32)w2 >= (u32)NV) w2 = 1;
      u16 hv = f2b(embed[(size_t)w2*NE + k]);
      xgru[b*KX + k] = hv;
      xread[b*KR + k] = hv;
    }
    return;
  }
  const int b = blockIdx.x;
  const int lane = tid&63, wv = tid>>6;
  __shared__ float red[4];
  __shared__ float bc1, bc2;
  const float* e = energy + (size_t)b*NV;
  float mx = -INFINITY;
  for (int i=tid;i<NV;i+=256) mx = fmaxf(mx, e[i]);
  for (int off=32; off; off>>=1) mx = fmaxf(mx, __shfl_xor(mx, off));
  if (lane==0) red[wv]=mx;
  __syncthreads();
  if (tid==0) bc1 = fmaxf(fmaxf(red[0],red[1]), fmaxf(red[2],red[3]));
  __syncthreads();
  const float M = bc1;
  float sm=0.f;
  for (int i=tid;i<NV;i+=256) sm += __expf(e[i]-M);
  for (int off=32; off; off>>=1) sm += __shfl_xor(sm, off);
  if (lane==0) red[wv]=sm;
  __syncthreads();
  if (tid==0) bc2 = red[0]+red[1]+red[2]+red[3];
  __syncthreads();
  const float LSE = M + __logf(bc2);
  const float omp = 1.f - pcb[b];
  float* ob = out + ((size_t)b*NT + t)*(NV+NL);
  for (int i=tid;i<NV;i+=256) ob[i] = __logf(omp*__expf(e[i]-LSE) + 1e-12f);
}

// ---------------- launch ----------------

extern "C" void kernel_launch(void* const* d_in, const int* in_sizes, int n_in,
                              void* d_out, int out_size, void* d_ws, size_t ws_size,
                              hipStream_t stream){
  const float* enc   = (const float*)d_in[0];
  const float* s_in  = (const float*)d_in[1];
  const int*   src   = (const int*)d_in[2];
  const int*   tgt   = (const int*)d_in[3];
  const float* embed = (const float*)d_in[4];
  const float* W_ih  = (const float*)d_in[5];
  const float* b_ih  = (const float*)d_in[6];
  const float* W_hh  = (const float*)d_in[7];
  const float* b_hh  = (const float*)d_in[8];
  const float* attWh = (const float*)d_in[9];
  const float* attWs = (const float*)d_in[10];
  const float* attb  = (const float*)d_in[11];
  const float* attv  = (const float*)d_in[12];
  const float* copyW = (const float*)d_in[13];
  const float* copyb = (const float*)d_in[14];
  const float* readW = (const float*)d_in[15];
  const float* readb = (const float*)d_in[16];
  const float* readWo= (const float*)d_in[17];
  float* out = (float*)d_out;
  (void)in_sizes; (void)n_in; (void)out_size; (void)ws_size;

  char* wsp = (char*)d_ws;
  size_t off = 0;
  auto alloc = [&](size_t bytes)->char*{ char* p = wsp + off; off = (off + bytes + 255) & ~(size_t)255; return p; };
  u16* enc_bf    = (u16*)alloc((size_t)NB*NL*NHE*2);
  u16* eproj     = (u16*)alloc((size_t)NB*NL*NA*2);
  u16* Wih_bf    = (u16*)alloc((size_t)1536*KX*2);
  u16* Whh_bf    = (u16*)alloc((size_t)1536*NHD*2);
  u16* attWh_bf  = (u16*)alloc((size_t)NA*NHE*2);
  u16* WsT_bf    = (u16*)alloc((size_t)NHD*NA*2);
  u16* readW_bf  = (u16*)alloc((size_t)NHD*KR*2);
  u16* readWo_bf = (u16*)alloc((size_t)NVP*256*2);
  u16* xgru      = (u16*)alloc((size_t)NB*KX*2);
  u16* xread     = (u16*)alloc((size_t)NB*KR*2);
  float* sbuf0   = (float*)alloc((size_t)NB*NHD*4);
  float* sbuf1   = (float*)alloc((size_t)NB*NHD*4);
  float* gi      = (float*)alloc((size_t)NB*1536*4);
  float* gh      = (float*)alloc((size_t)NB*1536*4);
  u16* mbf       = (u16*)alloc((size_t)NB*256*2);
  float* energy  = (float*)alloc((size_t)NB*NV*4);
  float* pcb     = (float*)alloc((size_t)NB*4);

  k_conv_flat<<<4096,256,0,stream>>>(enc, enc_bf, (long)NB*NL*NHE);
  k_conv_flat<<<512,256,0,stream>>>(W_hh, Whh_bf, (long)1536*NHD);
  k_conv_flat<<<256,256,0,stream>>>(attWh, attWh_bf, (long)NA*NHE);
  k_convpad<<<2048,256,0,stream>>>(W_ih, Wih_bf, 1536, 812, KX, (long)1536*KX);
  k_conv_readW<<<1024,256,0,stream>>>(readW, readW_bf);
  k_convpad<<<2048,256,0,stream>>>(readWo, readWo_bf, NV, 256, 256, (long)NVP*256);
  k_wst<<<1024,256,0,stream>>>(attWs, WsT_bf);
  k_init<<<682,256,0,stream>>>(s_in, embed, sbuf0, xgru, xread);
  k_encproj<<<dim3(4,400),256,0,stream>>>(enc_bf, attWh_bf, eproj);

  for (int t=0;t<NT;t++){
    const float* s_old = (t&1) ? sbuf1 : sbuf0;
    float* s_new = (t&1) ? sbuf0 : sbuf1;
    k_gru_gemm<<<24,256,0,stream>>>(xgru, xread, Wih_bf, Whh_bf, gi, gh);
    k_gru_elem<<<256,256,0,stream>>>(gi, gh, b_ih, b_hh, s_old, s_new, xread);
    k_attn<<<128,512,0,stream>>>(s_new, eproj, enc_bf, WsT_bf, attb, attv, src, copyW, copyb,
                                 xgru, xread, pcb, out, t);
    k_read_maxout<<<4,256,0,stream>>>(xread, readW_bf, readb, mbf);
    k_energy<<<157,256,0,stream>>>(mbf, readWo_bf, energy);
    k_out_emb<<<278,256,0,stream>>>(energy, pcb, out, t, tgt, embed, xgru, xread);
  }
}

// Round 2
// 4090.630 us; speedup vs baseline: 1.3318x; 1.3318x over previous
//
#include <hip/hip_runtime.h>

typedef unsigned short u16;
typedef unsigned int u32;
typedef short bf16x8 __attribute__((ext_vector_type(8)));
typedef float f32x4 __attribute__((ext_vector_type(4)));

#define NB 128
#define NL 400
#define NT 30
#define NE 300
#define KE 320     // padded emb K
#define NHE 512
#define NHD 512
#define NA 512
#define NV 20000
#define NVP 20096
#define K1 1024    // [s, ctx]
#define N1 2048    // W1 rows: rz(1024) | hn(512) | in_ctx(512)
#define NW 2048    // Wemb rows: Wih_emb(1536) | readW_emb(512)
#define OUTW (NV+NL)

static __device__ __forceinline__ u16 f2b(float x){ u32 u=__float_as_uint(x); u += 0x7FFFu + ((u>>16)&1u); return (u16)(u>>16); }
static __device__ __forceinline__ float b2f(u16 h){ return __uint_as_float(((u32)h)<<16); }
static __device__ __forceinline__ float fsig(float x){ return 1.f/(1.f+__expf(-x)); }
static __device__ __forceinline__ float ftanh(float x){ return 1.f - 2.f/(__expf(2.f*x)+1.f); }

static __device__ __forceinline__ void gll16(const u16* g, u16* l){
  __builtin_amdgcn_global_load_lds((const __attribute__((address_space(1))) void*)g,
                                   (__attribute__((address_space(3))) void*)l, 16, 0, 0);
}

// 128x128 output tile, A[M,K] x B[N,K] (both row-major bf16), f32 accum.
static __device__ __forceinline__ void gemm_core(const u16* A, int lda, const u16* Bm, int ldb,
                                                 int K, u16* lsA, u16* lsB, f32x4 (&acc)[4][4]){
  const int tid = threadIdx.x;
  const int wave = tid>>6, lane = tid&63;
  const int srow = lane>>2, sko = (lane&3)*8;
  const int wm = wave>>1, wn = wave&1;
#pragma unroll
  for (int i=0;i<4;i++)
#pragma unroll
    for (int j=0;j<4;j++)
#pragma unroll
      for (int q=0;q<4;q++) acc[i][j][q] = 0.f;
  for (int kt=0; kt<K; kt+=32){
#pragma unroll
    for (int i=0;i<2;i++){
      const int c = wave*2+i;
      const int row = c*16 + srow;
      gll16(A + (size_t)row*lda + kt + sko, lsA + c*512);
      gll16(Bm + (size_t)row*ldb + kt + sko, lsB + c*512);
    }
    __syncthreads();
    bf16x8 aF[4], bF[4];
#pragma unroll
    for (int mi=0;mi<4;mi++) aF[mi] = *(const bf16x8*)(lsA + (wm*64+mi*16+(lane&15))*32 + (lane>>4)*8);
#pragma unroll
    for (int nj=0;nj<4;nj++) bF[nj] = *(const bf16x8*)(lsB + (wn*64+nj*16+(lane&15))*32 + (lane>>4)*8);
#pragma unroll
    for (int mi=0;mi<4;mi++)
#pragma unroll
      for (int nj=0;nj<4;nj++)
        acc[mi][nj] = __builtin_amdgcn_mfma_f32_16x16x32_bf16(aF[mi], bF[nj], acc[mi][nj], 0,0,0);
    __syncthreads();
  }
}

// ---------------- setup kernels ----------------

__global__ __launch_bounds__(256) void k_conv_flat(const float* __restrict__ s, u16* __restrict__ d, long n){
  long i = (long)blockIdx.x*256 + threadIdx.x;
  const long st = (long)gridDim.x*256;
  for (; i<n; i+=st) d[i] = f2b(s[i]);
}

__global__ __launch_bounds__(256) void k_convpad(const float* __restrict__ s, u16* __restrict__ d,
                                                 int srows, int sk, int dk, long total){
  long i = (long)blockIdx.x*256 + threadIdx.x;
  const long st = (long)gridDim.x*256;
  for (; i<total; i+=st){
    int r = (int)(i / dk), k = (int)(i - (long)r*dk);
    d[i] = (r < srows && k < sk) ? f2b(s[(size_t)r*sk + k]) : (u16)0;
  }
}

// att_Ws (A x Hd) -> WsT (Hd x A)
__global__ __launch_bounds__(256) void k_wst(const float* __restrict__ s, u16* __restrict__ d){
  int idx = blockIdx.x*256 + threadIdx.x;
  if (idx < 512*512){
    int a = idx & 511, kk = idx >> 9;
    d[idx] = f2b(s[(size_t)a*512 + kk]);
  }
}

// W1[2048][1024]: rows 0..1024: [Whh_rz | Wih_ctx_rz]; 1024..1536: [Whh_n | 0]; 1536..2048: [0 | Wih_ctx_n]
__global__ __launch_bounds__(256) void k_build_w1(const float* __restrict__ Whh, const float* __restrict__ Wih, u16* __restrict__ d){
  int idx = blockIdx.x*256 + threadIdx.x;
  if (idx >= N1*K1) return;
  int n = idx >> 10, k = idx & 1023;
  float v = 0.f;
  if (n < 1024)       v = (k<512) ? Whh[(size_t)n*512 + k] : Wih[(size_t)n*812 + 300 + (k-512)];
  else if (n < 1536)  v = (k<512) ? Whh[(size_t)n*512 + k] : 0.f;
  else                v = (k<512) ? 0.f : Wih[(size_t)(n-512)*812 + 300 + (k-512)];
  d[idx] = f2b(v);
}

// W2[512][1024]: [read_W_s (cols 812..1324) | read_W_ctx (cols 300..812)]
__global__ __launch_bounds__(256) void k_build_w2(const float* __restrict__ Wr, u16* __restrict__ d){
  int idx = blockIdx.x*256 + threadIdx.x;
  if (idx >= 512*K1) return;
  int r = idx >> 10, k = idx & 1023;
  float v = (k<512) ? Wr[(size_t)r*1324 + 812 + k] : Wr[(size_t)r*1324 + 300 + (k-512)];
  d[idx] = f2b(v);
}

// Wemb[2048][320]: rows 0..1536 = Wih[:,0:300]; rows 1536..2048 = read_W[:,0:300]; k>=300 pad 0
__global__ __launch_bounds__(256) void k_build_wemb(const float* __restrict__ Wih, const float* __restrict__ Wr, u16* __restrict__ d){
  int idx = blockIdx.x*256 + threadIdx.x;
  if (idx >= NW*KE) return;
  int n = idx / KE, k = idx - n*KE;
  float v = 0.f;
  if (k < NE) v = (n < 1536) ? Wih[(size_t)n*812 + k] : Wr[(size_t)(n-1536)*1324 + k];
  d[idx] = f2b(v);
}

// Xemb[30*128][320]: word_t = t==0 ? SOS : clip(tgt[b][t-1])
__global__ __launch_bounds__(256) void k_build_xemb(const int* __restrict__ tgt, const float* __restrict__ embed, u16* __restrict__ d){
  int idx = blockIdx.x*256 + threadIdx.x;
  if (idx >= NT*NB*KE) return;
  int row = idx / KE, k = idx - row*KE;
  int t = row >> 7, b = row & 127;
  u16 hv = 0;
  if (k < NE){
    int w = 2;
    if (t > 0){ w = tgt[b*NT + t-1]; if ((u32)w >= (u32)NV) w = 1; }
    hv = f2b(embed[(size_t)w*NE + k]);
  }
  d[idx] = hv;
}

__global__ __launch_bounds__(256) void k_init(const float* __restrict__ s_in, float* __restrict__ sbuf0, u16* __restrict__ x1){
  int idx = blockIdx.x*256 + threadIdx.x;
  if (idx < 65536){
    int b = idx>>9, j = idx&511;
    float v = s_in[idx];
    sbuf0[idx] = v;
    x1[(size_t)b*K1 + j] = f2b(v);
  } else if (idx < 131072){
    int k = idx - 65536;
    int b = k>>9, j = k&511;
    x1[(size_t)b*K1 + 512 + j] = 0;
  }
}

// enc_proj = enc @ att_Wh^T, bf16. grid (4,400)
__global__ __launch_bounds__(256) void k_encproj(const u16* __restrict__ A, const u16* __restrict__ Bw, u16* __restrict__ C){
  __shared__ __align__(16) u16 lsA[4096], lsB[4096];
  const int n0 = blockIdx.x*128, m0 = blockIdx.y*128;
  f32x4 acc[4][4];
  gemm_core(A + (size_t)m0*512, 512, Bw + (size_t)n0*512, 512, 512, lsA, lsB, acc);
  const int tid=threadIdx.x, wave=tid>>6, lane=tid&63, wm=wave>>1, wn=wave&1;
#pragma unroll
  for (int mi=0;mi<4;mi++)
#pragma unroll
    for (int nj=0;nj<4;nj++)
#pragma unroll
      for (int q=0;q<4;q++){
        int r = m0 + wm*64 + mi*16 + (lane>>4)*4 + q;
        int c = n0 + wn*64 + nj*16 + (lane&15);
        C[(size_t)r*512 + c] = f2b(acc[mi][nj][q]);
      }
}

// gre = Xemb @ Wemb^T, f32 [3840][2048]. grid (16,30)
__global__ __launch_bounds__(256) void k_gemm_emb(const u16* __restrict__ Xe, const u16* __restrict__ We, float* __restrict__ gre){
  __shared__ __align__(16) u16 lsA[4096], lsB[4096];
  const int n0 = blockIdx.x*128, m0 = blockIdx.y*128;
  f32x4 acc[4][4];
  gemm_core(Xe + (size_t)m0*KE, KE, We + (size_t)n0*KE, KE, KE, lsA, lsB, acc);
  const int tid=threadIdx.x, wave=tid>>6, lane=tid&63, wm=wave>>1, wn=wave&1;
#pragma unroll
  for (int mi=0;mi<4;mi++)
#pragma unroll
    for (int nj=0;nj<4;nj++)
#pragma unroll
      for (int q=0;q<4;q++){
        int r = m0 + wm*64 + mi*16 + (lane>>4)*4 + q;
        int c = n0 + wn*64 + nj*16 + (lane&15);
        gre[(size_t)r*NW + c] = acc[mi][nj][q];
      }
}

// g = x1 @ W1^T, f32 [128][2048]. standalone (prologue, grid 16)
static __device__ __forceinline__ void gemm1_epilogue(float* __restrict__ g, int n0, f32x4 (&acc)[4][4]){
  const int tid=threadIdx.x, wave=tid>>6, lane=tid&63, wm=wave>>1, wn=wave&1;
#pragma unroll
  for (int mi=0;mi<4;mi++)
#pragma unroll
    for (int nj=0;nj<4;nj++)
#pragma unroll
      for (int q=0;q<4;q++){
        int r = wm*64 + mi*16 + (lane>>4)*4 + q;
        int c = n0 + wn*64 + nj*16 + (lane&15);
        g[(size_t)r*N1 + c] = acc[mi][nj][q];
      }
}

__global__ __launch_bounds__(256) void k_gemm1(const u16* __restrict__ x1, const u16* __restrict__ W1, float* __restrict__ g){
  __shared__ __align__(16) u16 lsA[4096], lsB[4096];
  const int n0 = blockIdx.x*128;
  f32x4 acc[4][4];
  gemm_core(x1, K1, W1 + (size_t)n0*K1, K1, K1, lsA, lsB, acc);
  gemm1_epilogue(g, n0, acc);
}

// ---------------- per-step kernels ----------------

// K2: GRU elementwise (dup x2) + q proj + e scores for 200 l's. grid 256, 512 thr
__global__ __launch_bounds__(512) void k_gru_e(const float* __restrict__ g, const float* __restrict__ gre,
    const float* __restrict__ bih, const float* __restrict__ bhh,
    const float* __restrict__ s_old, float* __restrict__ s_new, u16* __restrict__ x1,
    const u16* __restrict__ WsT, const float* __restrict__ attb, const float* __restrict__ attv,
    const u16* __restrict__ eproj, const int* __restrict__ src, float* __restrict__ e_ws, int t){
  const int tid = threadIdx.x;
  const int b = blockIdx.x >> 1, y = blockIdx.x & 1;
  __shared__ float s_lds[512];
  __shared__ float q_lds[512];
  const float* gb = g + (size_t)b*N1;
  const float* ge = gre + ((size_t)(t*NB + b))*NW;
  {
    const int j = tid;
    float r = fsig(gb[j] + ge[j] + bih[j] + bhh[j]);
    float z = fsig(gb[512+j] + ge[512+j] + bih[512+j] + bhh[512+j]);
    float n = ftanh(ge[1024+j] + gb[1536+j] + bih[1024+j] + r*(gb[1024+j] + bhh[1024+j]));
    float sn = (1.f-z)*n + z*s_old[(size_t)b*512 + j];
    s_lds[j] = sn;
    if (y==0){ s_new[(size_t)b*512 + j] = sn; x1[(size_t)b*K1 + j] = f2b(sn); }
  }
  __syncthreads();
  {
    float a0=0,a1=0,a2=0,a3=0;
    const u16* wp = WsT + tid;
#pragma unroll 4
    for (int k=0;k<512;k+=4){
      a0 += s_lds[k]   * b2f(wp[(size_t)k*512]);
      a1 += s_lds[k+1] * b2f(wp[(size_t)(k+1)*512]);
      a2 += s_lds[k+2] * b2f(wp[(size_t)(k+2)*512]);
      a3 += s_lds[k+3] * b2f(wp[(size_t)(k+3)*512]);
    }
    q_lds[tid] = attb[tid] + a0+a1+a2+a3;
  }
  __syncthreads();
  const int lane = tid&63, wv = tid>>6;
  float v8[8], q8[8];
#pragma unroll
  for (int j=0;j<8;j++){ v8[j]=attv[lane*8+j]; q8[j]=q_lds[lane*8+j]; }
#pragma unroll 2
  for (int i=0;i<25;i++){
    const int l = y*200 + wv + 8*i;
    const u16* ep = eproj + ((size_t)b*NL + l)*512 + lane*8;
    const uint4 pk = *(const uint4*)ep;
    const u32 wsv[4] = {pk.x, pk.y, pk.z, pk.w};
    float acc=0;
#pragma unroll
    for (int j2=0;j2<4;j2++){
      float x0 = b2f((u16)(wsv[j2]&0xFFFFu)) + q8[2*j2];
      float x1v = b2f((u16)(wsv[j2]>>16))    + q8[2*j2+1];
      acc += v8[2*j2]*ftanh(x0) + v8[2*j2+1]*ftanh(x1v);
    }
    for (int off=32; off; off>>=1) acc += __shfl_xor(acc, off);
    if (lane==0) e_ws[(size_t)b*NL + l] = (src[b*NL + l]==0) ? -INFINITY : acc;
  }
}

// K3: softmax + ctx + p_copy + copy-slice output. grid 128, 512 thr
__global__ __launch_bounds__(512) void k_attn2(const float* __restrict__ e_ws, const u16* __restrict__ encb,
    const float* __restrict__ s_new, const float* __restrict__ copyW, const float* __restrict__ copyb,
    u16* __restrict__ x1, float* __restrict__ pcb, float* __restrict__ out, int t){
  const int tid = threadIdx.x, b = blockIdx.x;
  const int lane = tid&63, wv = tid>>6;
  __shared__ float a_lds[NL];
  __shared__ float red[8];
  __shared__ float bc1, bc2, bc3;
  float ev = (tid<NL)? e_ws[(size_t)b*NL + tid] : -INFINITY;
  float mx = ev;
  for (int off=32; off; off>>=1) mx = fmaxf(mx, __shfl_xor(mx, off));
  if (lane==0) red[wv]=mx;
  __syncthreads();
  if (tid==0){ float m=red[0]; for(int i=1;i<8;i++) m=fmaxf(m,red[i]); bc1=m; }
  __syncthreads();
  float p = (tid<NL)? __expf(ev - bc1) : 0.f;
  float sm = p;
  for (int off=32; off; off>>=1) sm += __shfl_xor(sm, off);
  if (lane==0) red[wv]=sm;
  __syncthreads();
  if (tid==0){ float s2=0; for(int i=0;i<8;i++) s2+=red[i]; bc2=s2; }
  __syncthreads();
  if (tid<NL) a_lds[tid] = p / bc2;
  __syncthreads();
  float c0=0,c1=0,c2=0,c3=0;
  const u16* eb = encb + (size_t)b*NL*512 + tid;
#pragma unroll 4
  for (int l=0;l<NL;l+=4){
    c0 += a_lds[l]   * b2f(eb[(size_t)l*512]);
    c1 += a_lds[l+1] * b2f(eb[(size_t)(l+1)*512]);
    c2 += a_lds[l+2] * b2f(eb[(size_t)(l+2)*512]);
    c3 += a_lds[l+3] * b2f(eb[(size_t)(l+3)*512]);
  }
  const float ctx = c0+c1+c2+c3;
  x1[(size_t)b*K1 + 512 + tid] = f2b(ctx);
  float part = s_new[(size_t)b*512 + tid]*copyW[tid] + ctx*copyW[512+tid];
  for (int off=32; off; off>>=1) part += __shfl_xor(part, off);
  if (lane==0) red[wv]=part;
  __syncthreads();
  if (tid==0){ float s2=0; for(int i=0;i<8;i++) s2+=red[i]; bc3 = fsig(s2 + copyb[0]); pcb[b]=bc3; }
  __syncthreads();
  const float pcv = bc3;
  if (tid<NL) out[((size_t)b*NT + t)*OUTW + NV + tid] = __logf(pcv*a_lds[tid] + 1e-12f);
}

// K4: rvec = rvec_emb + x1 @ W2^T (+bias), maxout -> mbf. grid 4
__global__ __launch_bounds__(256) void k_read(const u16* __restrict__ x1, const u16* __restrict__ W2,
    const float* __restrict__ gre, const float* __restrict__ readb, u16* __restrict__ mbf, int t){
  __shared__ __align__(16) u16 lsA[4096], lsB[4096];
  const int n0 = blockIdx.x*128;
  f32x4 acc[4][4];
  gemm_core(x1, K1, W2 + (size_t)n0*K1, K1, K1, lsA, lsB, acc);
  const int tid=threadIdx.x, wave=tid>>6, lane=tid&63, wm=wave>>1, wn=wave&1;
#pragma unroll
  for (int mi=0;mi<4;mi++)
#pragma unroll
    for (int nj=0;nj<4;nj++)
#pragma unroll
      for (int q=0;q<4;q++){
        int r = wm*64 + mi*16 + (lane>>4)*4 + q;
        int c = n0 + wn*64 + nj*16 + (lane&15);
        float v = acc[mi][nj][q] + readb[c] + gre[((size_t)(t*NB + r))*NW + 1536 + c];
        float o = __shfl_xor(v, 1);
        float mx2 = fmaxf(v, o);
        if (!(lane&1)) mbf[(size_t)r*256 + (c>>1)] = f2b(mx2);
      }
}

// K5: energy = m @ Wo^T (+ per-row exp-sum partials). grid 157
__global__ __launch_bounds__(256) void k_energy(const u16* __restrict__ mbf, const u16* __restrict__ Wo,
    float* __restrict__ energy, float* __restrict__ parts){
  __shared__ __align__(16) u16 lsA[4096], lsB[4096];
  __shared__ float psum[128][2];
  const int n0 = blockIdx.x*128;
  f32x4 acc[4][4];
  gemm_core(mbf, 256, Wo + (size_t)n0*256, 256, 256, lsA, lsB, acc);
  const int tid=threadIdx.x, wave=tid>>6, lane=tid&63, wm=wave>>1, wn=wave&1;
  float rs[4][4];
#pragma unroll
  for (int mi=0;mi<4;mi++)
#pragma unroll
    for (int q=0;q<4;q++) rs[mi][q]=0.f;
#pragma unroll
  for (int mi=0;mi<4;mi++)
#pragma unroll
    for (int nj=0;nj<4;nj++){
      const int c = n0 + wn*64 + nj*16 + (lane&15);
#pragma unroll
      for (int q=0;q<4;q++){
        const int r = wm*64 + mi*16 + (lane>>4)*4 + q;
        float e = acc[mi][nj][q];
        if (c < NV){ energy[(size_t)r*NV + c] = e; rs[mi][q] += __expf(e); }
      }
    }
#pragma unroll
  for (int mi=0;mi<4;mi++)
#pragma unroll
    for (int q=0;q<4;q++){
      float v = rs[mi][q];
      v += __shfl_xor(v,1); v += __shfl_xor(v,2); v += __shfl_xor(v,4); v += __shfl_xor(v,8);
      if ((lane&15)==0) psum[wm*64 + mi*16 + (lane>>4)*4 + q][wn] = v;
    }
  __syncthreads();
  if (tid < 128) parts[(size_t)tid*160 + blockIdx.x] = psum[tid][0] + psum[tid][1];
}

// K6: vocab log-probs for step t + gemm1 for step t+1. grid 272
__global__ __launch_bounds__(256) void k_outg(const float* __restrict__ energy, const float* __restrict__ parts,
    const float* __restrict__ pcb, float* __restrict__ out, int t,
    const u16* __restrict__ x1, const u16* __restrict__ W1, float* __restrict__ g, int do_g){
  __shared__ __align__(16) u16 lsA[4096], lsB[4096];
  const int bx = blockIdx.x, tid = threadIdx.x;
  if (bx >= 256){
    if (!do_g) return;
    const int n0 = (bx-256)*128;
    f32x4 acc[4][4];
    gemm_core(x1, K1, W1 + (size_t)n0*K1, K1, K1, lsA, lsB, acc);
    gemm1_epilogue(g, n0, acc);
    return;
  }
  const int b = bx>>1, half = bx&1;
  const int lane = tid&63, wv = tid>>6;
  __shared__ float red[4];
  __shared__ float bcL, bcO;
  float v = (tid<157)? parts[(size_t)b*160 + tid] : 0.f;
  for (int off=32; off; off>>=1) v += __shfl_xor(v, off);
  if (lane==0) red[wv]=v;
  __syncthreads();
  if (tid==0){ bcL = __logf(red[0]+red[1]+red[2]+red[3]); bcO = 1.f - pcb[b]; }
  __syncthreads();
  const float LSE = bcL, omp = bcO;
  float* ob = out + ((size_t)b*NT + t)*OUTW + half*10000;
  const float* eb = energy + (size_t)b*NV + half*10000;
  for (int i=tid; i<10000; i+=256) ob[i] = __logf(omp*__expf(eb[i]-LSE) + 1e-12f);
}

// ---------------- launch ----------------

extern "C" void kernel_launch(void* const* d_in, const int* in_sizes, int n_in,
                              void* d_out, int out_size, void* d_ws, size_t ws_size,
                              hipStream_t stream){
  const float* enc   = (const float*)d_in[0];
  const float* s_in  = (const float*)d_in[1];
  const int*   src   = (const int*)d_in[2];
  const int*   tgt   = (const int*)d_in[3];
  const float* embed = (const float*)d_in[4];
  const float* W_ih  = (const float*)d_in[5];
  const float* b_ih  = (const float*)d_in[6];
  const float* W_hh  = (const float*)d_in[7];
  const float* b_hh  = (const float*)d_in[8];
  const float* attWh = (const float*)d_in[9];
  const float* attWs = (const float*)d_in[10];
  const float* attb  = (const float*)d_in[11];
  const float* attv  = (const float*)d_in[12];
  const float* copyW = (const float*)d_in[13];
  const float* copyb = (const float*)d_in[14];
  const float* readW = (const float*)d_in[15];
  const float* readb = (const float*)d_in[16];
  const float* readWo= (const float*)d_in[17];
  float* out = (float*)d_out;
  (void)in_sizes; (void)n_in; (void)out_size; (void)ws_size;

  char* wsp = (char*)d_ws;
  size_t off = 0;
  auto alloc = [&](size_t bytes)->char*{ char* p = wsp + off; off = (off + bytes + 255) & ~(size_t)255; return p; };
  u16* enc_bf   = (u16*)alloc((size_t)NB*NL*NHE*2);
  u16* eproj    = (u16*)alloc((size_t)NB*NL*NA*2);
  u16* attWh_bf = (u16*)alloc((size_t)NA*NHE*2);
  u16* WsT      = (u16*)alloc((size_t)NHD*NA*2);
  u16* W1       = (u16*)alloc((size_t)N1*K1*2);
  u16* W2       = (u16*)alloc((size_t)512*K1*2);
  u16* Wemb     = (u16*)alloc((size_t)NW*KE*2);
  u16* Xemb     = (u16*)alloc((size_t)NT*NB*KE*2);
  u16* WoP      = (u16*)alloc((size_t)NVP*256*2);
  float* gre    = (float*)alloc((size_t)NT*NB*NW*4);
  float* g      = (float*)alloc((size_t)NB*N1*4);
  u16* x1       = (u16*)alloc((size_t)NB*K1*2);
  float* sbufA  = (float*)alloc((size_t)NB*NHD*4);
  float* sbufB  = (float*)alloc((size_t)NB*NHD*4);
  float* e_ws   = (float*)alloc((size_t)NB*NL*4);
  u16* mbf      = (u16*)alloc((size_t)NB*256*2);
  float* energy = (float*)alloc((size_t)NB*NV*4);
  float* parts  = (float*)alloc((size_t)NB*160*4);
  float* pcb    = (float*)alloc((size_t)NB*4);

  k_conv_flat<<<4096,256,0,stream>>>(enc, enc_bf, (long)NB*NL*NHE);
  k_conv_flat<<<1024,256,0,stream>>>(attWh, attWh_bf, (long)NA*NHE);
  k_wst<<<1024,256,0,stream>>>(attWs, WsT);
  k_build_w1<<<8192,256,0,stream>>>(W_hh, W_ih, W1);
  k_build_w2<<<2048,256,0,stream>>>(readW, W2);
  k_build_wemb<<<2560,256,0,stream>>>(W_ih, readW, Wemb);
  k_build_xemb<<<4800,256,0,stream>>>(tgt, embed, Xemb);
  k_convpad<<<2048,256,0,stream>>>(readWo, WoP, NV, 256, 256, (long)NVP*256);
  k_init<<<512,256,0,stream>>>(s_in, sbufA, x1);
  k_encproj<<<dim3(4,400),256,0,stream>>>(enc_bf, attWh_bf, eproj);
  k_gemm_emb<<<dim3(16,30),256,0,stream>>>(Xemb, Wemb, gre);
  k_gemm1<<<16,256,0,stream>>>(x1, W1, g);

  for (int t=0; t<NT; t++){
    const float* s_old = (t&1) ? sbufB : sbufA;
    float* s_new       = (t&1) ? sbufA : sbufB;
    k_gru_e<<<256,512,0,stream>>>(g, gre, b_ih, b_hh, s_old, s_new, x1, WsT, attb, attv,
                                  eproj, src, e_ws, t);
    k_attn2<<<128,512,0,stream>>>(e_ws, enc_bf, s_new, copyW, copyb, x1, pcb, out, t);
    k_read<<<4,256,0,stream>>>(x1, W2, gre, readb, mbf, t);
    k_energy<<<157,256,0,stream>>>(mbf, WoP, energy, parts);
    k_outg<<<272,256,0,stream>>>(energy, parts, pcb, out, t, x1, W1, g, (t+1<NT) ? 1 : 0);
  }
}